// Round 10
// baseline (715.113 us; speedup 1.0000x reference)
//
#include <hip/hip_runtime.h>

// InductionNetwork capsule routing, C=256, K=64, H=1024, 3 iterations.
// R17: 4 dispatches with intra-dispatch producer->consumer flags.
// R15 hung because its grids (704/640 blocks) exceeded co-residency
// capacity -> spinning consumers starved unplaced producers. R17 enforces
// a PROVABLE bound: all kernels are uniform 1024-thr blocks with
// __launch_bounds__(1024,8) (VGPR<=64) and LDS<=70.2KB -> exactly 2
// blocks/CU -> capacity 512; every grid <=456. Capacity >= grid with
// uniform demand => every block is resident before any spin => deadlock-
// free for ANY dispatch order. Flag protocol itself proven (R13/R14
// passed). Boundaries 7 -> 3 (~12us each, the dominant cost per R12-R16).
//   D1 [0,64) convWt ; [64,200) Q=WtWt^T 136 tri tiles (waits wtcnt=64,
//      mirror-writes) ; [200,456) routing0
//   D2 [0,128) y=Qs -> ycnt1[mt] ; [128,192) convWb->Wx ; [192,448)
//      routing1 (waits ycnt1[c>>6]==32)
//   D3 [0,128) y=Qs -> ycnt2 ; [128,384) routing2 (waits)
//   D4 [0,128) chat=Ws (B=Wb) -> chatcnt ; [128,384) squash (waits) -> out
// Race-safety: routing_i overwrites s-panel mt only after all 32 gemm
// blocks of panel mt published (they read s before publishing).
// Routing body = R12-exact (186us baseline; pin experiments were nulls).
// Split-bf16 operands (verified R6-R16, absmax 4.88e-4):
//   D = Ah.Bh + Ah.Bl + Al.Bh with hi=bf16(x), lo=bf16(x-hi).
// Fallback: R3's proven monolithic kernel if ws too small.

using f32x4  = __attribute__((ext_vector_type(4))) float;
using f32x2  = __attribute__((ext_vector_type(2))) float;
using bf16x8 = __attribute__((ext_vector_type(8))) __bf16;
using bf16x4 = __attribute__((ext_vector_type(4))) __bf16;

struct BfPair { __bf16 hi, lo; };
__device__ inline BfPair split_bf16(float x) {
    BfPair p;
    p.hi = (__bf16)x;
    p.lo = (__bf16)(x - (float)p.hi);
    return p;
}

// ---------------- LDS shapes ------------------------------------------------
struct RoutSM {
    float spart[16][1024];  // 64 KB: per-wave partial s
    float u_s[1024];        //  4 KB: y staged for the dots
    float b_s[64], d_s[64], red_s[16], scale_s;
};
struct QSmem {
    __bf16 a_hi[64 * 64];
    __bf16 a_lo[64 * 64];
    __bf16 b_hi[64 * 64];
    __bf16 b_lo[64 * 64];
};

// ---------------- point-to-point sync (protocol proven R13/R14) -------------
__device__ inline void publish_count(unsigned* f) {
    __syncthreads();                    // all block stores issued
    if (threadIdx.x == 0) {
        __threadfence();                // release to device scope
        __hip_atomic_fetch_add(f, 1u, __ATOMIC_ACQ_REL,
                               __HIP_MEMORY_SCOPE_AGENT);
    }
}
__device__ inline void wait_count(const unsigned* f, unsigned target) {
    if (threadIdx.x == 0)
        while (__hip_atomic_load(f, __ATOMIC_ACQUIRE,
                                 __HIP_MEMORY_SCOPE_AGENT) < target)
            __builtin_amdgcn_s_sleep(2);
    __syncthreads();
    __threadfence();                    // acquire: drop stale lines
}

// ---------------- routing body (R12-exact, 186us-proven) --------------------
// Block = capsule c, 16 waves. Wave w owns enc rows w*4..w*4+3; lane holds
// 16 floats/row. MODE 0: d uniform. MODE 1: b = scale*(E.y). MODE 2: +=.
template <int MODE>
__device__ __forceinline__ void routing_body(
    int c, const float* __restrict__ enc, const float* __restrict__ y0,
    const float* __restrict__ y1, float* __restrict__ bglob,
    __bf16* __restrict__ s_hi, __bf16* __restrict__ s_lo, RoutSM* sm)
{
    const int t = threadIdx.x, lane = t & 63, w = t >> 6;   // 16 waves
    const float* E = enc + (size_t)c * 65536;

    // small prologue loads first so their waitcnt doesn't drain er loads
    float yv = 0.f, sv = 0.f;
    if (MODE > 0) {
        const size_t o = (size_t)c * 1024 + t;
        yv = y0[o] + y1[o];                       // y = Q s (full K)
        sv = (float)s_hi[o] + (float)s_lo[o];     // s as the gemm saw it
    }

    f32x4 er[4][4];                     // enc tile
    #pragma unroll
    for (int r = 0; r < 4; ++r) {
        const float* ek = E + (size_t)(w * 4 + r) * 1024 + lane * 8;
        er[r][0] = *(const f32x4*)(ek);
        er[r][1] = *(const f32x4*)(ek + 4);
        er[r][2] = *(const f32x4*)(ek + 512);
        er[r][3] = *(const f32x4*)(ek + 516);
    }

    if (MODE > 0) {
        sm->u_s[t] = yv;
        float p = yv * sv;                        // norm = s^T Q s = |W s|^2
        #pragma unroll
        for (int off = 32; off; off >>= 1) p += __shfl_xor(p, off, 64);
        if (lane == 0) sm->red_s[w] = p;
        __syncthreads();
        if (t == 0) {
            float n = 0.f;
            #pragma unroll
            for (int i = 0; i < 16; ++i) n += sm->red_s[i];
            sm->scale_s = n / ((1.f + n) * sqrtf(n) + 1e-30f);
        }
        __syncthreads();
        const float scale = sm->scale_s;
        f32x4 uf[4];
        uf[0] = *(const f32x4*)&sm->u_s[lane * 8];
        uf[1] = *(const f32x4*)&sm->u_s[lane * 8 + 4];
        uf[2] = *(const f32x4*)&sm->u_s[512 + lane * 8];
        uf[3] = *(const f32x4*)&sm->u_s[512 + lane * 8 + 4];
        #pragma unroll
        for (int r = 0; r < 4; ++r) {
            float sum = 0.f;
            #pragma unroll
            for (int q = 0; q < 4; ++q)
                #pragma unroll
                for (int j = 0; j < 4; ++j)
                    sum += er[r][q][j] * uf[q][j];
            #pragma unroll
            for (int off = 32; off; off >>= 1) sum += __shfl_xor(sum, off, 64);
            if (lane == 0) {
                const int k = w * 4 + r;
                const float bv =
                    (MODE == 2 ? bglob[c * 64 + k] : 0.f) + scale * sum;
                bglob[c * 64 + k] = bv;     // persist for next iteration
                sm->b_s[k] = bv;
            }
        }
    }
    __syncthreads();

    if (MODE == 0) {
        if (t < 64) sm->d_s[t] = 1.f / 64.f;
    } else if (t < 64) {
        float bv = sm->b_s[t], m = bv;
        #pragma unroll
        for (int off = 32; off; off >>= 1) m = fmaxf(m, __shfl_xor(m, off, 64));
        const float e = expf(bv - m);
        float smm = e;
        #pragma unroll
        for (int off = 32; off; off >>= 1) smm += __shfl_xor(smm, off, 64);
        sm->d_s[t] = e / smm;
    }
    __syncthreads();

    // per-wave partial s from registers (4 rows each)
    #pragma unroll
    for (int q = 0; q < 4; ++q) {
        f32x4 p = {};
        #pragma unroll
        for (int r = 0; r < 4; ++r) {
            const float dk = sm->d_s[w * 4 + r];
            #pragma unroll
            for (int j = 0; j < 4; ++j) p[j] += dk * er[r][q][j];
        }
        const int h = (q >> 1) * 512 + lane * 8 + (q & 1) * 4;
        *(f32x4*)&sm->spart[w][h] = p;
    }
    __syncthreads();

    // cross-wave reduce: 1 h-element per thread; emit split-bf16 s
    {
        float a = 0.f;
        #pragma unroll
        for (int wv = 0; wv < 16; ++wv) a += sm->spart[wv][t];
        const BfPair p = split_bf16(a);
        s_hi[(size_t)c * 1024 + t] = p.hi;
        s_lo[(size_t)c * 1024 + t] = p.lo;
    }
}

// ---------------- 16-wave 64x64 split-bf16 NT GEMM tile (R13-verified) ------
// 16 waves in a 4x4 grid, one 16x16 frag each; BK=64 LDS staging,
// XOR-swizzled 128-B rows. Threads [0,512) stage A rows, [512,1024) B rows.
// WQ=1: write split-bf16 Q (+ mirror if mirror!=0); WQ=0: write float C.
__device__ __forceinline__ int swz128(int row, int colbyte) {
    return row * 128 + (colbyte ^ ((row & 7) << 4));
}

template <int WQ>
__device__ __forceinline__ void gemm64_16w(
    const __bf16* __restrict__ Ah, const __bf16* __restrict__ Al,
    const __bf16* __restrict__ Bh, const __bf16* __restrict__ Bl,
    int arow0, int brow0, int kbeg, int kend,
    float* __restrict__ Cc, __bf16* __restrict__ Qh, __bf16* __restrict__ Ql,
    int crow0, int ccol0, int mirror, QSmem* sm)
{
    const int t = threadIdx.x, lane = t & 63, w = t >> 6;
    const int wr = w >> 2, wc = w & 3;          // 4x4 wave grid
    const int half = t >> 9;                    // 0: stage A, 1: stage B
    const int sr   = (t & 511) >> 3;            // row 0..63
    const int scb  = (t & 7) * 16;              // col byte 0..112
    const __bf16* sh = half ? Bh : Ah;
    const __bf16* sl = half ? Bl : Al;
    const size_t g = (size_t)((half ? brow0 : arow0) + sr) * 1024 + scb / 2;
    char* const p_hi = (char*)(half ? sm->b_hi : sm->a_hi) + swz128(sr, scb);
    char* const p_lo = (char*)(half ? sm->b_lo : sm->a_lo) + swz128(sr, scb);

    f32x4 acc = {};
    for (int k0 = kbeg; k0 < kend; k0 += 64) {
        __syncthreads();                        // prev LDS use done
        *(bf16x8*)p_hi = *(const bf16x8*)(sh + g + k0);
        *(bf16x8*)p_lo = *(const bf16x8*)(sl + g + k0);
        __syncthreads();
        #pragma unroll
        for (int kk = 0; kk < 2; ++kk) {
            const int cb = kk * 64 + (lane >> 4) * 16;
            const int m = wr * 16 + (lane & 15);
            const int n = wc * 16 + (lane & 15);
            const bf16x8 ah = *(const bf16x8*)((char*)sm->a_hi + swz128(m, cb));
            const bf16x8 al = *(const bf16x8*)((char*)sm->a_lo + swz128(m, cb));
            const bf16x8 bh = *(const bf16x8*)((char*)sm->b_hi + swz128(n, cb));
            const bf16x8 bl = *(const bf16x8*)((char*)sm->b_lo + swz128(n, cb));
            acc = __builtin_amdgcn_mfma_f32_16x16x32_bf16(ah, bh, acc, 0, 0, 0);
            acc = __builtin_amdgcn_mfma_f32_16x16x32_bf16(ah, bl, acc, 0, 0, 0);
            acc = __builtin_amdgcn_mfma_f32_16x16x32_bf16(al, bh, acc, 0, 0, 0);
        }
    }
    const int rr = (lane >> 4) * 4, colb = lane & 15;
    if (WQ) {
        bf16x4 hv, lv;
        #pragma unroll
        for (int r = 0; r < 4; ++r) {
            const BfPair p = split_bf16(acc[r]);
            const size_t idx = (size_t)(crow0 + wr * 16 + rr + r) * 1024 +
                               ccol0 + wc * 16 + colb;
            Qh[idx] = p.hi;
            Ql[idx] = p.lo;
            hv[r] = p.hi;
            lv[r] = p.lo;
        }
        if (mirror) {   // Q symmetric: packed 8B store into the transpose
            const size_t midx = (size_t)(ccol0 + wc * 16 + colb) * 1024 +
                                crow0 + wr * 16 + rr;
            *(bf16x4*)(Qh + midx) = hv;
            *(bf16x4*)(Ql + midx) = lv;
        }
    } else {
        #pragma unroll
        for (int r = 0; r < 4; ++r)
            Cc[(size_t)(crow0 + wr * 16 + rr + r) * 1024 +
               ccol0 + wc * 16 + colb] = acc[r];
    }
}

// ---------------- D1: convWt | Q (tri, waits) | routing0 --------------------
__global__ __launch_bounds__(1024, 8) void d1_kernel(
    const float* __restrict__ enc, const float* __restrict__ W,
    float* __restrict__ bglob,
    __bf16* __restrict__ s_hi, __bf16* __restrict__ s_lo,
    __bf16* __restrict__ Wt_hi, __bf16* __restrict__ Wt_lo,
    __bf16* __restrict__ Q_hi, __bf16* __restrict__ Q_lo,
    unsigned* __restrict__ flg)
{
    __shared__ union { RoutSM r; QSmem q; float tile[64][65]; } sm;
    const int b = blockIdx.x, t = threadIdx.x;
    unsigned* wtcnt = flg + 0;

    if (b < 64) {                       // convWt: 4 transpose tiles each
        for (int rep = 0; rep < 4; ++rep) {
            const int tile = b * 4 + rep;
            const int by = tile >> 4, bx = tile & 15;
            const int tx = t & 63, ty = t >> 6;
            if (rep) __syncthreads();
            for (int i = ty; i < 64; i += 16)
                sm.tile[i][tx] = W[(size_t)(by * 64 + i) * 1024 + bx * 64 + tx];
            __syncthreads();
            for (int i = ty; i < 64; i += 16) {
                const size_t idx = (size_t)(bx * 64 + i) * 1024 + by * 64 + tx;
                const BfPair p = split_bf16(sm.tile[tx][i]);
                Wt_hi[idx] = p.hi;
                Wt_lo[idx] = p.lo;
            }
        }
        publish_count(wtcnt);
    } else if (b < 200) {               // Q: 136 triangular tiles
        const int qb = b - 64;
        int tj = (int)((sqrtf(8.f * (float)qb + 1.f) - 1.f) * 0.5f);
        while ((tj + 1) * (tj + 2) / 2 <= qb) ++tj;
        while (tj * (tj + 1) / 2 > qb) --tj;
        const int ti = qb - tj * (tj + 1) / 2;
        wait_count(wtcnt, 64);
        gemm64_16w<1>(Wt_hi, Wt_lo, Wt_hi, Wt_lo, ti * 64, tj * 64, 0, 1024,
                      nullptr, Q_hi, Q_lo, ti * 64, tj * 64, ti != tj, &sm.q);
    } else {                            // routing0
        routing_body<0>(b - 200, enc, nullptr, nullptr, bglob,
                        s_hi, s_lo, &sm.r);
    }
}

// ---------------- D2: gemm_y0 | convWb | routing1 (waits) -------------------
__global__ __launch_bounds__(1024, 8) void d2_kernel(
    const float* __restrict__ enc, const float* __restrict__ W,
    float* __restrict__ bglob,
    __bf16* __restrict__ s_hi, __bf16* __restrict__ s_lo,
    float* __restrict__ y0, float* __restrict__ y1,
    __bf16* __restrict__ Wb_hi, __bf16* __restrict__ Wb_lo,
    const __bf16* __restrict__ Q_hi, const __bf16* __restrict__ Q_lo,
    unsigned* __restrict__ flg)
{
    __shared__ union { RoutSM r; QSmem q; } sm;
    const int b = blockIdx.x, t = threadIdx.x;
    unsigned* ycnt1 = flg + 8;          // 4 counters (per 64-row panel)

    if (b < 128) {                      // y = Q s, split-K x2
        const int kh = b & 1, task = b >> 1;
        const int mt = task >> 4, nt = task & 15;
        gemm64_16w<0>(s_hi, s_lo, Q_hi, Q_lo, mt * 64, nt * 64,
                      kh * 512, kh * 512 + 512, kh ? y1 : y0,
                      nullptr, nullptr, mt * 64, nt * 64, 0, &sm.q);
        publish_count(ycnt1 + mt);
    } else if (b < 192) {               // convWb into the dead Wt buffer
        const int bb = b - 128;         // 64 blocks x 16 rows
        #pragma unroll
        for (int q = 0; q < 16; ++q) {
            const size_t idx = (size_t)bb * 16384 + (size_t)q * 1024 + t;
            const BfPair p = split_bf16(W[idx]);
            Wb_hi[idx] = p.hi;
            Wb_lo[idx] = p.lo;
        }
    } else {                            // routing1 (waits its y panel)
        const int c = b - 192;
        wait_count(ycnt1 + (c >> 6), 32);
        routing_body<1>(c, enc, y0, y1, bglob, s_hi, s_lo, &sm.r);
    }
}

// ---------------- D3: gemm_y1 | routing2 (waits) ----------------------------
__global__ __launch_bounds__(1024, 8) void d3_kernel(
    const float* __restrict__ enc, float* __restrict__ bglob,
    __bf16* __restrict__ s_hi, __bf16* __restrict__ s_lo,
    float* __restrict__ y0, float* __restrict__ y1,
    const __bf16* __restrict__ Q_hi, const __bf16* __restrict__ Q_lo,
    unsigned* __restrict__ flg)
{
    __shared__ union { RoutSM r; QSmem q; } sm;
    const int b = blockIdx.x;
    unsigned* ycnt2 = flg + 16;

    if (b < 128) {
        const int kh = b & 1, task = b >> 1;
        const int mt = task >> 4, nt = task & 15;
        gemm64_16w<0>(s_hi, s_lo, Q_hi, Q_lo, mt * 64, nt * 64,
                      kh * 512, kh * 512 + 512, kh ? y1 : y0,
                      nullptr, nullptr, mt * 64, nt * 64, 0, &sm.q);
        publish_count(ycnt2 + mt);
    } else {
        const int c = b - 128;
        wait_count(ycnt2 + (c >> 6), 32);
        routing_body<2>(c, enc, y0, y1, bglob, s_hi, s_lo, &sm.r);
    }
}

// ---------------- D4: gemm_chat | squash (waits) -> out ---------------------
__global__ __launch_bounds__(1024, 8) void d4_kernel(
    const __bf16* __restrict__ s_hi, const __bf16* __restrict__ s_lo,
    float* __restrict__ y0, float* __restrict__ y1,
    const __bf16* __restrict__ Wb_hi, const __bf16* __restrict__ Wb_lo,
    float* __restrict__ outp, unsigned* __restrict__ flg)
{
    __shared__ union { QSmem q; float red[16]; } sm;
    const int b = blockIdx.x, t = threadIdx.x;
    unsigned* chatcnt = flg + 24;

    if (b < 128) {                      // chat = W s (B = Wb)
        const int kh = b & 1, task = b >> 1;
        const int mt = task >> 4, nt = task & 15;
        gemm64_16w<0>(s_hi, s_lo, Wb_hi, Wb_lo, mt * 64, nt * 64,
                      kh * 512, kh * 512 + 512, kh ? y1 : y0,
                      nullptr, nullptr, mt * 64, nt * 64, 0, &sm.q);
        publish_count(chatcnt + mt);
    } else {                            // squash -> out
        const int c = b - 128;
        wait_count(chatcnt + (c >> 6), 32);
        const int lane = t & 63, w = t >> 6;
        const size_t o = (size_t)c * 1024 + t;
        const float v = y0[o] + y1[o];
        float ss = v * v;
        #pragma unroll
        for (int off = 32; off; off >>= 1) ss += __shfl_xor(ss, off, 64);
        if (lane == 0) sm.red[w] = ss;
        __syncthreads();
        float norm = 0.f;
        #pragma unroll
        for (int i = 0; i < 16; ++i) norm += sm.red[i];
        const float scale = norm / ((1.f + norm) * sqrtf(norm) + 1e-30f);
        outp[o] = v * scale;
    }
}

// ---------------- fallback: R3's proven monolithic fp32 kernel --------------
__global__ __launch_bounds__(512) void fallback_kernel(
    const float* __restrict__ enc, const float* __restrict__ W,
    float* __restrict__ outp)
{
    __shared__ float u_s[1024], s_s[1024], c_s[1024], chat_s[1024];
    __shared__ float b_s[64], d_s[64], red_s[8];
    const int t = threadIdx.x, lane = t & 63, w = t >> 6;
    const float* erow = enc + (size_t)blockIdx.x * 65536;

    if (t < 64) b_s[t] = 0.f;
    __syncthreads();

    for (int it = 0; it < 3; ++it) {
        if (it > 0) {
            f32x4 uf[4];
            #pragma unroll
            for (int q = 0; q < 2; ++q) {
                uf[2*q]   = *(const f32x4*)&u_s[q*512 + lane*8];
                uf[2*q+1] = *(const f32x4*)&u_s[q*512 + lane*8 + 4];
            }
            for (int r = 0; r < 8; ++r) {
                const int k = w * 8 + r;
                const float* ek = erow + (size_t)k * 1024;
                float sum = 0.f;
                #pragma unroll
                for (int q = 0; q < 2; ++q) {
                    f32x4 e0 = *(const f32x4*)(ek + q*512 + lane*8);
                    f32x4 e1 = *(const f32x4*)(ek + q*512 + lane*8 + 4);
                    #pragma unroll
                    for (int j = 0; j < 4; ++j) {
                        sum += e0[j] * uf[2*q][j];
                        sum += e1[j] * uf[2*q+1][j];
                    }
                }
                #pragma unroll
                for (int off = 32; off; off >>= 1) sum += __shfl_xor(sum, off, 64);
                if (lane == 0) b_s[k] += sum;
            }
            __syncthreads();
        }
        if (t < 64) {
            float bv = b_s[t], m = bv;
            #pragma unroll
            for (int off = 32; off; off >>= 1) m = fmaxf(m, __shfl_xor(m, off, 64));
            float e = expf(bv - m), sm = e;
            #pragma unroll
            for (int off = 32; off; off >>= 1) sm += __shfl_xor(sm, off, 64);
            d_s[t] = e / sm;
        }
        __syncthreads();
        {
            const int h0 = t * 2;
            float a0 = 0.f, a1 = 0.f;
            for (int k = 0; k < 64; ++k) {
                f32x2 ev = *(const f32x2*)(erow + (size_t)k * 1024 + h0);
                a0 += d_s[k] * ev[0]; a1 += d_s[k] * ev[1];
            }
            s_s[h0] = a0; s_s[h0+1] = a1;
        }
        __syncthreads();
        {
            f32x4 sf[4];
            #pragma unroll
            for (int q = 0; q < 2; ++q) {
                sf[2*q]   = *(const f32x4*)&s_s[q*512 + lane*8];
                sf[2*q+1] = *(const f32x4*)&s_s[q*512 + lane*8 + 4];
            }
            for (int r = 0; r < 128; ++r) {
                const int d = w * 128 + r;
                const float* wr = W + (size_t)d * 1024;
                float sum = 0.f;
                #pragma unroll
                for (int q = 0; q < 2; ++q) {
                    f32x4 w0 = *(const f32x4*)(wr + q*512 + lane*8);
                    f32x4 w1 = *(const f32x4*)(wr + q*512 + lane*8 + 4);
                    #pragma unroll
                    for (int j = 0; j < 4; ++j) {
                        sum += w0[j] * sf[2*q][j];
                        sum += w1[j] * sf[2*q+1][j];
                    }
                }
                #pragma unroll
                for (int off = 32; off; off >>= 1) sum += __shfl_xor(sum, off, 64);
                if (lane == 0) chat_s[d] = sum;
            }
        }
        __syncthreads();
        {
            const int h0 = t * 2;
            float v0 = chat_s[h0], v1 = chat_s[h0+1];
            float ss = v0*v0 + v1*v1;
            #pragma unroll
            for (int off = 32; off; off >>= 1) ss += __shfl_xor(ss, off, 64);
            if (lane == 0) red_s[w] = ss;
            __syncthreads();
            float norm = 0.f;
            #pragma unroll
            for (int i = 0; i < 8; ++i) norm += red_s[i];
            const float scale = norm / ((1.f + norm) * sqrtf(norm) + 1e-30f);
            c_s[h0] = v0 * scale; c_s[h0+1] = v1 * scale;
        }
        __syncthreads();
        if (it < 2) {
            const int h0 = t * 2;
            float uu0 = 0.f, uu1 = 0.f;
            for (int d = 0; d < 1024; ++d) {
                f32x2 wv = *(const f32x2*)(W + (size_t)d * 1024 + h0);
                uu0 += c_s[d] * wv[0]; uu1 += c_s[d] * wv[1];
            }
            u_s[h0] = uu0; u_s[h0+1] = uu1;
        } else {
            const int h0 = t * 2;
            f32x2 ov; ov[0] = c_s[h0]; ov[1] = c_s[h0+1];
            *(f32x2*)(outp + (size_t)blockIdx.x * 1024 + h0) = ov;
        }
        __syncthreads();
    }
}

extern "C" void kernel_launch(void* const* d_in, const int* in_sizes, int n_in,
                              void* d_out, int out_size, void* d_ws, size_t ws_size,
                              hipStream_t stream)
{
    const float* enc = (const float*)d_in[0];   // [256,64,1024] fp32
    const float* W   = (const float*)d_in[1];   // [1024,1024]   fp32
    float* outp = (float*)d_out;                // [256,1024]    fp32
    (void)in_sizes; (void)n_in; (void)out_size;

    // ws layout (11.5 MB + flag words)
    char* ws = (char*)d_ws;
    float*    b     = (float*)   (ws + 0x000000);  //  64 KB [256,64]
    __bf16*   s_hi  = (__bf16*)  (ws + 0x080000);  // 512 KB [256,1024]
    __bf16*   s_lo  = (__bf16*)  (ws + 0x100000);  // 512 KB
    float*    y0    = (float*)   (ws + 0x180000);  //   1 MB (y / chat lo-K)
    float*    y1    = (float*)   (ws + 0x280000);  //   1 MB (y / chat hi-K)
    __bf16*   Wx_hi = (__bf16*)  (ws + 0x380000);  //   2 MB  Wt then Wb
    __bf16*   Wx_lo = (__bf16*)  (ws + 0x580000);  //   2 MB
    __bf16*   Q_hi  = (__bf16*)  (ws + 0x780000);  //   2 MB [1024,1024]
    __bf16*   Q_lo  = (__bf16*)  (ws + 0x980000);  //   2 MB
    unsigned* flg   = (unsigned*)(ws + 0xB80000);  //   4 KB flags

    if (ws_size < 0xB81000) {
        fallback_kernel<<<256, 512, 0, stream>>>(enc, W, outp);
        return;
    }

    // zero the flags (ws is poison-filled by the harness each run)
    hipMemsetAsync(flg, 0, 4096, stream);

    // D1: convWt | Q (triangular, waits wtcnt) | routing0        (456 blocks)
    d1_kernel<<<456, 1024, 0, stream>>>(
        enc, W, b, s_hi, s_lo, Wx_hi, Wx_lo, Q_hi, Q_lo, flg);

    // D2: gemm_y0 | convWb | routing1 (waits ycnt1)              (448 blocks)
    d2_kernel<<<448, 1024, 0, stream>>>(
        enc, W, b, s_hi, s_lo, y0, y1, Wx_hi, Wx_lo, Q_hi, Q_lo, flg);

    // D3: gemm_y1 | routing2 (waits ycnt2)                       (384 blocks)
    d3_kernel<<<384, 1024, 0, stream>>>(
        enc, b, s_hi, s_lo, y0, y1, Q_hi, Q_lo, flg);

    // D4: gemm_chat | squash (waits chatcnt) -> out              (384 blocks)
    d4_kernel<<<384, 1024, 0, stream>>>(
        s_hi, s_lo, y0, y1, Wx_hi, Wx_lo, outp, flg);
}